// Round 1
// baseline (1923.425 us; speedup 1.0000x reference)
//
#include <hip/hip_runtime.h>
#include <hip/hip_bf16.h>
#include <math.h>

// Problem dims
#define VOCAB 400000
#define D     300
#define L     2000
#define B     4
#define C1    64
#define K1    3
#define C2    128
#define K2    500
#define HID   256
#define NCLS  5
#define NP1   1999   // pooled length after conv1+pool(300): floor((L*D-K1+1 - 300)/300)+1
#define T2    1500   // conv2 out length: NP1 - K2 + 1

// ---------------------------------------------------------------------------
// K1: fused embedding gather + conv1(1->64, k=3) + relu + maxpool(300)
// out1[b][c][p] = relu( max_{j in [0,300)} sum_k w1[c][k]*sig[b][300p+j+k] + b1[c] )
// sig[b][i] = emb[x[b][i/300]][i%300]; window p spans row p (300) + 2 elems of row p+1.
// ---------------------------------------------------------------------------
__global__ __launch_bounds__(256) void k1_embed_conv1_pool(
    const int* __restrict__ x, const float* __restrict__ emb,
    const float* __restrict__ w1, const float* __restrict__ b1,
    float* __restrict__ out1)
{
    int blk = blockIdx.x;            // b*NP1 + p
    int b = blk / NP1;
    int p = blk % NP1;
    __shared__ float sig[302];
    __shared__ float red[256];
    int tid = threadIdx.x;
    int row0 = x[b * L + p];
    int row1 = x[b * L + p + 1];     // p <= 1998 -> p+1 <= 1999 < L, always valid
    for (int i = tid; i < 302; i += 256) {
        sig[i] = (i < 300) ? emb[(size_t)row0 * D + i]
                           : emb[(size_t)row1 * D + (i - 300)];
    }
    __syncthreads();
    int c = tid & 63, g = tid >> 6;
    float w0 = w1[c * 3 + 0], w1v = w1[c * 3 + 1], w2v = w1[c * 3 + 2];
    float bb = b1[c];
    float m = -INFINITY;
    for (int j = g; j < 300; j += 4) {
        float v = fmaf(w0, sig[j], fmaf(w1v, sig[j + 1], fmaf(w2v, sig[j + 2], bb)));
        m = fmaxf(m, v);
    }
    red[tid] = m;
    __syncthreads();
    if (tid < 64) {
        float mm = fmaxf(fmaxf(red[tid], red[tid + 64]),
                         fmaxf(red[tid + 128], red[tid + 192]));
        out1[((size_t)b * C1 + tid) * NP1 + p] = fmaxf(mm, 0.0f);
    }
}

// ---------------------------------------------------------------------------
// K2: conv2 (64 -> 128, k=500). Register-blocked over 8 couts per thread.
// Each block: one batch b, 8 couts, 256 consecutive t. Input segment staged in
// LDS (one cin at a time); weights are block-uniform -> scalar loads.
// out2[b][co][t] (pre-relu; relu folded into pool kernel).
// ---------------------------------------------------------------------------
#define CTILE 8
__global__ __launch_bounds__(256) void k2_conv2(
    const float* __restrict__ in1, const float* __restrict__ w2,
    const float* __restrict__ b2, float* __restrict__ out2)
{
    int blk = blockIdx.x;            // b*96 + cg*6 + tc
    int b   = blk / 96;
    int rem = blk % 96;
    int cg  = rem / 6;
    int tc  = rem % 6;
    int cout0 = cg * CTILE;
    int t0 = tc * 256;
    __shared__ float seg[256 + K2 - 1];   // 755 floats
    int tid = threadIdx.x;
    int t = t0 + tid;
    bool valid = t < T2;
    int seg_len = min(256 + K2 - 1, NP1 - t0);
    float acc[CTILE];
#pragma unroll
    for (int c = 0; c < CTILE; ++c) acc[c] = b2[cout0 + c];

    for (int cin = 0; cin < C1; ++cin) {
        __syncthreads();
        const float* src = in1 + ((size_t)b * C1 + cin) * NP1 + t0;
        for (int i = tid; i < seg_len; i += 256) seg[i] = src[i];
        __syncthreads();
        const float* wrow = w2 + ((size_t)cout0 * C1 + cin) * K2;
#pragma unroll 4
        for (int k = 0; k < K2; ++k) {
            float xv = seg[tid + k];     // <= 754, in-bounds; garbage only for invalid t
#pragma unroll
            for (int c = 0; c < CTILE; ++c)
                acc[c] = fmaf(xv, wrow[(size_t)c * (C1 * K2) + k], acc[c]);
        }
    }
    if (valid) {
#pragma unroll
        for (int c = 0; c < CTILE; ++c)
            out2[((size_t)b * C2 + cout0 + c) * T2 + t] = acc[c];
    }
}

// ---------------------------------------------------------------------------
// K2b: relu + maxpool(1500) -> h1[b][co]
// ---------------------------------------------------------------------------
__global__ __launch_bounds__(256) void k2b_pool(
    const float* __restrict__ out2, float* __restrict__ h1)
{
    int bc = blockIdx.x;             // b*C2 + co
    const float* row = out2 + (size_t)bc * T2;
    int tid = threadIdx.x;
    float m = -INFINITY;
    for (int t = tid; t < T2; t += 256) m = fmaxf(m, row[t]);
    __shared__ float red[256];
    red[tid] = m;
    __syncthreads();
    for (int s = 128; s > 0; s >>= 1) {
        if (tid < s) red[tid] = fmaxf(red[tid], red[tid + s]);
        __syncthreads();
    }
    if (tid == 0) h1[bc] = fmaxf(red[0], 0.0f);   // relu(max) == max(relu)
}

// ---------------------------------------------------------------------------
// K3: lin1 + relu + lin2 + softmax. One block per batch row.
// ---------------------------------------------------------------------------
__global__ __launch_bounds__(256) void k3_head(
    const float* __restrict__ h1,
    const float* __restrict__ wl1, const float* __restrict__ bl1,
    const float* __restrict__ wl2, const float* __restrict__ bl2,
    float* __restrict__ out)
{
    int b = blockIdx.x;
    int tid = threadIdx.x;
    __shared__ float xin[C2];
    __shared__ float hbuf[HID];
    __shared__ float lg[NCLS];
    if (tid < C2) xin[tid] = h1[b * C2 + tid];
    __syncthreads();
    float a = bl1[tid];
    for (int c = 0; c < C2; ++c) a = fmaf(xin[c], wl1[tid * C2 + c], a);
    hbuf[tid] = fmaxf(a, 0.0f);
    __syncthreads();
    if (tid < NCLS) {
        float l = bl2[tid];
        for (int j = 0; j < HID; ++j) l = fmaf(hbuf[j], wl2[tid * HID + j], l);
        lg[tid] = l;
    }
    __syncthreads();
    if (tid < NCLS) {
        float mx = lg[0];
        for (int i = 1; i < NCLS; ++i) mx = fmaxf(mx, lg[i]);
        float s = 0.f;
        for (int i = 0; i < NCLS; ++i) s += expf(lg[i] - mx);
        out[b * NCLS + tid] = expf(lg[tid] - mx) / s;
    }
}

extern "C" void kernel_launch(void* const* d_in, const int* in_sizes, int n_in,
                              void* d_out, int out_size, void* d_ws, size_t ws_size,
                              hipStream_t stream)
{
    const int*   x   = (const int*)  d_in[0];
    const float* emb = (const float*)d_in[1];
    const float* w1  = (const float*)d_in[2];
    const float* b1  = (const float*)d_in[3];
    const float* w2  = (const float*)d_in[4];
    const float* b2  = (const float*)d_in[5];
    const float* wl1 = (const float*)d_in[6];
    const float* bl1 = (const float*)d_in[7];
    const float* wl2 = (const float*)d_in[8];
    const float* bl2 = (const float*)d_in[9];
    float* out = (float*)d_out;

    float* ws  = (float*)d_ws;
    float* ws1 = ws;                       // in1:  B*C1*NP1 = 511744 floats
    float* ws2 = ws1 + (size_t)B * C1 * NP1; // out2: B*C2*T2 = 768000 floats
    float* h1  = ws2 + (size_t)B * C2 * T2;  // 512 floats

    hipLaunchKernelGGL(k1_embed_conv1_pool, dim3(B * NP1), dim3(256), 0, stream,
                       x, emb, w1, b1, ws1);
    hipLaunchKernelGGL(k2_conv2, dim3(B * (C2 / CTILE) * 6), dim3(256), 0, stream,
                       ws1, w2, b2, ws2);
    hipLaunchKernelGGL(k2b_pool, dim3(B * C2), dim3(256), 0, stream, ws2, h1);
    hipLaunchKernelGGL(k3_head, dim3(B), dim3(256), 0, stream,
                       h1, wl1, bl1, wl2, bl2, out);
}

// Round 2
// 212.507 us; speedup vs baseline: 9.0511x; 9.0511x over previous
//
#include <hip/hip_runtime.h>
#include <hip/hip_bf16.h>
#include <math.h>

// Problem dims
#define VOCAB 400000
#define D     300
#define L     2000
#define B     4
#define C1    64
#define K1    3
#define C2    128
#define K2    500
#define HID   256
#define NCLS  5
#define NP1   1999   // pooled length after conv1+pool(300)
#define T2    1500   // conv2 out length: NP1 - K2 + 1
#define TPAD  2048   // padded t-length for in1T
#define S     4      // cin split groups (16 cin each)
#define BN    96     // t per block tile
#define NTI   16     // t tiles (16*96 = 1536 >= 1500)
#define NK2   250    // k handled as 250 pairs (k = 2*k2 + klo)
#define SEGROWS 596  // BN + 499 + 1

typedef __attribute__((ext_vector_type(8))) short short8;
typedef __attribute__((ext_vector_type(4))) float f32x4;

// ---------------------------------------------------------------------------
// kT_w2: transpose conv2 weights fp32 [co][cin][k] -> bf16 aT[s][k2][co][kk]
// where kk = klo*16 + ci, cin = s*16+ci, k = 2*k2+klo. Coalesced via LDS tile.
// grid: 4(s) * 16(cog) * 5(kc) = 320 blocks
// ---------------------------------------------------------------------------
__global__ __launch_bounds__(256) void kT_w2(
    const float* __restrict__ w2, __hip_bfloat16* __restrict__ aT)
{
    int blk = blockIdx.x;
    int kc  = blk % 5;
    int cog = (blk / 5) % 16;
    int s   = blk / 80;
    __shared__ float tile[8 * 16 * 100];   // [co_l][ci][k_l] flat, 51.2 KB
    int tid = threadIdx.x;
    for (int i = tid; i < 12800; i += 256) {
        int row = i / 100, k = i % 100;    // row = co_l*16 + ci
        int co = cog * 8 + (row >> 4), ci = row & 15;
        tile[i] = w2[((size_t)co * C1 + s * 16 + ci) * K2 + kc * 100 + k];
    }
    __syncthreads();
    for (int j = tid; j < 12800; j += 256) {
        int kk  = j & 31;
        int co_l = (j >> 5) & 7;
        int k2l = j >> 8;                  // 0..49
        int ci = kk & 15, klo = kk >> 4;
        float v = tile[(co_l * 16 + ci) * 100 + 2 * k2l + klo];
        int k2 = kc * 50 + k2l;
        aT[(((size_t)s * NK2 + k2) * C2 + cog * 8 + co_l) * 32 + kk] =
            __float2bfloat16(v);
    }
}

// ---------------------------------------------------------------------------
// k1: fused embedding gather + conv1(1->64,k=3) + relu + maxpool(300)
// writes bf16 transposed: in1T[b][t][cin]  (t padded to 2048)
// ---------------------------------------------------------------------------
__global__ __launch_bounds__(256) void k1_embed_conv1_pool(
    const int* __restrict__ x, const float* __restrict__ emb,
    const float* __restrict__ w1, const float* __restrict__ b1,
    __hip_bfloat16* __restrict__ in1T)
{
    int blk = blockIdx.x;            // b*NP1 + p
    int b = blk / NP1;
    int p = blk % NP1;
    __shared__ float sig[302];
    __shared__ float red[256];
    int tid = threadIdx.x;
    int row0 = x[b * L + p];
    int row1 = x[b * L + p + 1];
    for (int i = tid; i < 302; i += 256) {
        sig[i] = (i < 300) ? emb[(size_t)row0 * D + i]
                           : emb[(size_t)row1 * D + (i - 300)];
    }
    __syncthreads();
    int c = tid & 63, g = tid >> 6;
    float w0 = w1[c * 3 + 0], w1v = w1[c * 3 + 1], w2v = w1[c * 3 + 2];
    float bb = b1[c];
    float m = -INFINITY;
    for (int j = g; j < 300; j += 4) {
        float v = fmaf(w0, sig[j], fmaf(w1v, sig[j + 1], fmaf(w2v, sig[j + 2], bb)));
        m = fmaxf(m, v);
    }
    red[tid] = m;
    __syncthreads();
    if (tid < 64) {
        float mm = fmaxf(fmaxf(red[tid], red[tid + 64]),
                         fmaxf(red[tid + 128], red[tid + 192]));
        in1T[((size_t)b * TPAD + p) * C1 + tid] = __float2bfloat16(fmaxf(mm, 0.0f));
    }
}

// zero-pad in1T rows 1999..2047 (read by tail t-tiles)
__global__ __launch_bounds__(256) void kpad(__hip_bfloat16* __restrict__ in1T)
{
    int i = blockIdx.x * 256 + threadIdx.x;     // 4*49*64 = 12544
    if (i < B * (TPAD - NP1) * C1) {
        int b = i / ((TPAD - NP1) * C1);
        int r = i % ((TPAD - NP1) * C1);
        in1T[((size_t)b * TPAD + NP1) * C1 + r] = __float2bfloat16(0.0f);
    }
}

// ---------------------------------------------------------------------------
// k2_mfma: conv2 as bf16 MFMA GEMM.
// D[co][t] += sum over (cin,k) of W[co][cin][k] * in1T[t+k][cin]
// MFMA 16x16x32: A = weights (rows=co), B = sliding im2col (cols=t),
// MFMA-k dim = kk = klo*16 + ci  (k = 2*k2+klo, cin = s*16+ci).
// Block: 128co x 96t x (16 cin group s), 4 waves of 64x48.
// grid = 256 (XCD-swizzled so each XCD caches one weight slice).
// ---------------------------------------------------------------------------
__global__ __launch_bounds__(256) void k2_mfma(
    const __hip_bfloat16* __restrict__ in1T,
    const __hip_bfloat16* __restrict__ aT,
    float* __restrict__ part)
{
    // XCD swizzle: 256 blocks, 8 XCDs -> XCD k gets wid k*32..k*32+31
    int wid = (blockIdx.x & 7) * 32 + (blockIdx.x >> 3);
    int s   = wid >> 6;            // cin group (2 XCDs per s)
    int rem = wid & 63;
    int b   = rem >> 4;
    int ti  = rem & 15;
    int t0  = ti * BN;

    __shared__ __align__(16) __hip_bfloat16 seg[SEGROWS * 16];   // 19072 B
    __shared__ __align__(16) __hip_bfloat16 abuf[2][C2 * 32];    // 2 x 8 KB

    int tid = threadIdx.x;
    int widx = tid >> 6;           // wave id 0..3
    int l    = tid & 63;
    int lane16 = l & 15;
    int g      = l >> 4;           // 0..3
    int klo    = g >> 1;           // row parity
    int cihalf = (g & 1) * 8;      // ci base within 16
    int co0w = (widx & 1) * 64;    // wave co base
    int tn0  = (widx >> 1) * 48;   // wave t base

    // stage B segment: in1T rows t0..t0+595, cin s*16..s*16+15
    for (int u = tid; u < SEGROWS * 2; u += 256) {
        int row = u >> 1, half = u & 1;
        const __hip_bfloat16* src =
            in1T + ((size_t)(b * TPAD + t0 + row) * C1 + s * 16 + half * 8);
        *reinterpret_cast<int4*>(&seg[row * 16 + half * 8]) =
            *reinterpret_cast<const int4*>(src);
    }

    // prologue: stage A slice k2=0
    const int4* asrc = reinterpret_cast<const int4*>(aT + (size_t)s * NK2 * 4096);
    int4 r0 = asrc[tid];
    int4 r1 = asrc[256 + tid];
    *reinterpret_cast<int4*>(&abuf[0][tid * 8]) = r0;
    *reinterpret_cast<int4*>(&abuf[0][2048 + tid * 8]) = r1;
    __syncthreads();

    f32x4 acc[4][3];
#pragma unroll
    for (int fa = 0; fa < 4; ++fa)
#pragma unroll
        for (int fb = 0; fb < 3; ++fb) acc[fa][fb] = (f32x4){0.f, 0.f, 0.f, 0.f};

    // per-lane LDS offsets
    int aoff[4];
#pragma unroll
    for (int fa = 0; fa < 4; ++fa)
        aoff[fa] = (co0w + fa * 16 + lane16) * 32 + g * 8;
    int boff[3];
#pragma unroll
    for (int fb = 0; fb < 3; ++fb)
        boff[fb] = (tn0 + fb * 16 + lane16 + klo) * 16 + cihalf;

    int cur = 0;
    for (int k2 = 0; k2 < NK2; ++k2) {
        if (k2 < NK2 - 1) {
            const int4* p = asrc + (size_t)(k2 + 1) * 512;
            r0 = p[tid];
            r1 = p[256 + tid];
        }
        short8 afr[4];
#pragma unroll
        for (int fa = 0; fa < 4; ++fa)
            afr[fa] = *reinterpret_cast<const short8*>(&abuf[cur][aoff[fa]]);
        short8 bfr[3];
#pragma unroll
        for (int fb = 0; fb < 3; ++fb)
            bfr[fb] = *reinterpret_cast<const short8*>(&seg[boff[fb] + k2 * 32]);
#pragma unroll
        for (int fa = 0; fa < 4; ++fa)
#pragma unroll
            for (int fb = 0; fb < 3; ++fb)
                acc[fa][fb] = __builtin_amdgcn_mfma_f32_16x16x32_bf16(
                    afr[fa], bfr[fb], acc[fa][fb], 0, 0, 0);
        if (k2 < NK2 - 1) {
            *reinterpret_cast<int4*>(&abuf[cur ^ 1][tid * 8]) = r0;
            *reinterpret_cast<int4*>(&abuf[cur ^ 1][2048 + tid * 8]) = r1;
        }
        __syncthreads();
        cur ^= 1;
    }

    // epilogue: D row = 4*g + r (co within 16), col = lane16 (t within 16)
#pragma unroll
    for (int fa = 0; fa < 4; ++fa) {
#pragma unroll
        for (int fb = 0; fb < 3; ++fb) {
            int t = t0 + tn0 + fb * 16 + lane16;
            if (t < T2) {
                int cobase = co0w + fa * 16 + 4 * g;
#pragma unroll
                for (int r = 0; r < 4; ++r) {
                    part[(((size_t)s * B + b) * C2 + cobase + r) * T2 + t] =
                        acc[fa][fb][r];
                }
            }
        }
    }
}

// ---------------------------------------------------------------------------
// k2b: sum 4 cin-group partials + bias, relu+maxpool(1500) -> h1[b][co]
// ---------------------------------------------------------------------------
__global__ __launch_bounds__(256) void k2b_pool(
    const float* __restrict__ part, const float* __restrict__ b2,
    float* __restrict__ h1)
{
    int bc = blockIdx.x;             // b*C2 + co
    int b = bc / C2, co = bc % C2;
    const float* p0 = part + (((size_t)0 * B + b) * C2 + co) * T2;
    const float* p1 = part + (((size_t)1 * B + b) * C2 + co) * T2;
    const float* p2 = part + (((size_t)2 * B + b) * C2 + co) * T2;
    const float* p3 = part + (((size_t)3 * B + b) * C2 + co) * T2;
    int tid = threadIdx.x;
    float m = -INFINITY;
    for (int t = tid; t < T2; t += 256)
        m = fmaxf(m, p0[t] + p1[t] + p2[t] + p3[t]);
    __shared__ float red[256];
    red[tid] = m;
    __syncthreads();
    for (int sft = 128; sft > 0; sft >>= 1) {
        if (tid < sft) red[tid] = fmaxf(red[tid], red[tid + sft]);
        __syncthreads();
    }
    if (tid == 0) h1[bc] = fmaxf(red[0] + b2[co], 0.0f);
}

// ---------------------------------------------------------------------------
// k3: lin1 + relu + lin2 + softmax. One block per batch row.
// ---------------------------------------------------------------------------
__global__ __launch_bounds__(256) void k3_head(
    const float* __restrict__ h1,
    const float* __restrict__ wl1, const float* __restrict__ bl1,
    const float* __restrict__ wl2, const float* __restrict__ bl2,
    float* __restrict__ out)
{
    int b = blockIdx.x;
    int tid = threadIdx.x;
    __shared__ float xin[C2];
    __shared__ float hbuf[HID];
    __shared__ float lg[NCLS];
    if (tid < C2) xin[tid] = h1[b * C2 + tid];
    __syncthreads();
    float a = bl1[tid];
    for (int c = 0; c < C2; ++c) a = fmaf(xin[c], wl1[tid * C2 + c], a);
    hbuf[tid] = fmaxf(a, 0.0f);
    __syncthreads();
    if (tid < NCLS) {
        float lv = bl2[tid];
        for (int j = 0; j < HID; ++j) lv = fmaf(hbuf[j], wl2[tid * HID + j], lv);
        lg[tid] = lv;
    }
    __syncthreads();
    if (tid < NCLS) {
        float mx = lg[0];
        for (int i = 1; i < NCLS; ++i) mx = fmaxf(mx, lg[i]);
        float sum = 0.f;
        for (int i = 0; i < NCLS; ++i) sum += expf(lg[i] - mx);
        out[b * NCLS + tid] = expf(lg[tid] - mx) / sum;
    }
}

extern "C" void kernel_launch(void* const* d_in, const int* in_sizes, int n_in,
                              void* d_out, int out_size, void* d_ws, size_t ws_size,
                              hipStream_t stream)
{
    const int*   x   = (const int*)  d_in[0];
    const float* emb = (const float*)d_in[1];
    const float* w1  = (const float*)d_in[2];
    const float* b1  = (const float*)d_in[3];
    const float* w2  = (const float*)d_in[4];
    const float* b2  = (const float*)d_in[5];
    const float* wl1 = (const float*)d_in[6];
    const float* bl1 = (const float*)d_in[7];
    const float* wl2 = (const float*)d_in[8];
    const float* bl2 = (const float*)d_in[9];
    float* out = (float*)d_out;

    // workspace layout (floats):
    // part: S*B*C2*T2 = 3,072,000 | h1: 512 | in1T: 524288 bf16 | aT: 4,096,000 bf16
    float* ws   = (float*)d_ws;
    float* part = ws;
    float* h1   = ws + (size_t)S * B * C2 * T2;
    __hip_bfloat16* in1T = (__hip_bfloat16*)(h1 + 512);
    __hip_bfloat16* aT   = in1T + (size_t)B * TPAD * C1;

    hipLaunchKernelGGL(kT_w2, dim3(320), dim3(256), 0, stream, w2, aT);
    hipLaunchKernelGGL(k1_embed_conv1_pool, dim3(B * NP1), dim3(256), 0, stream,
                       x, emb, w1, b1, in1T);
    hipLaunchKernelGGL(kpad, dim3(49), dim3(256), 0, stream, in1T);
    hipLaunchKernelGGL(k2_mfma, dim3(256), dim3(256), 0, stream, in1T, aT, part);
    hipLaunchKernelGGL(k2b_pool, dim3(B * C2), dim3(256), 0, stream, part, b2, h1);
    hipLaunchKernelGGL(k3_head, dim3(B), dim3(256), 0, stream,
                       h1, wl1, bl1, wl2, bl2, out);
}

// Round 3
// 103.462 us; speedup vs baseline: 18.5907x; 2.0540x over previous
//
#include <hip/hip_runtime.h>
#include <hip/hip_bf16.h>
#include <math.h>

// Problem dims
#define VOCAB 400000
#define D     300
#define L     2000
#define B     4
#define C1    64
#define C2    128
#define K2    500
#define HID   256
#define NCLS  5
#define NP1   1999   // pooled length after conv1+pool(300)
#define T2    1500   // conv2 out length
#define TPAD  2304   // padded t-length (B staging reads up to t0+767 = 2207)
#define S     8      // cin split groups (8 cin each)
#define CI    8      // cin per group
#define NK2   125    // MFMA K-steps per block: k = 4*k2 + g, K=32 per step
#define BN    96     // t per block tile
#define NKT   1600   // weight-transpose blocks: 8 s * 25 kc * 8 cog

typedef __attribute__((ext_vector_type(8))) short short8v;
typedef __attribute__((ext_vector_type(4))) float f32x4;

__device__ __forceinline__ void gload_lds16(const void* g, void* l) {
    __builtin_amdgcn_global_load_lds(
        (const __attribute__((address_space(1))) void*)g,
        (__attribute__((address_space(3))) void*)l, 16, 0, 0);
}

// ---------------------------------------------------------------------------
// k_prep: fused [weight transpose] + [embed+conv1+relu+pool].
// Blocks [0,1600): aT[s][k2][g][co][e] = w2[co][s*8+e][4*k2+g]  (bf16)
//   -> per (s,k2): 4 g-blocks of 128co x 8e = 16B units; A-frag ds_read of
//      16 lanes is 256B contiguous => conflict-free.
// Blocks [1600,1600+7996): in1T[b][sg][t][ci] = relu(maxpool(conv1(emb)))
//   16-B rows => B-frag reads conflict-free, B staging contiguous.
// ---------------------------------------------------------------------------
__global__ __launch_bounds__(256) void k_prep(
    const int* __restrict__ x, const float* __restrict__ emb,
    const float* __restrict__ w1, const float* __restrict__ b1,
    const float* __restrict__ w2,
    __hip_bfloat16* __restrict__ in1T, __hip_bfloat16* __restrict__ aT)
{
    __shared__ float smem[2560];   // kT tile: 16co x 8ci x 20k ; k1: sig+red
    int bid = blockIdx.x, tid = threadIdx.x;
    if (bid < NKT) {
        // ---- weight transpose: s(8) x kc(25, 5 k2 each = 20 k) x cog(8, 16 co)
        int s  = bid / 200;
        int rem = bid % 200;
        int kc = rem / 8, cog = rem % 8;
        int co0 = cog * 16;
        for (int i = tid; i < 2560; i += 256) {
            int co_l = i / 160, r = i % 160, ci = r / 20, kl = r % 20;
            smem[i] = w2[((size_t)(co0 + co_l) * C1 + s * CI + ci) * K2 + kc * 20 + kl];
        }
        __syncthreads();
        for (int u = tid; u < 320; u += 256) {
            int co_l = u & 15, gk = u >> 4;      // gk 0..19
            int g = gk & 3, k2l = gk >> 2;       // k2l 0..4
            __hip_bfloat16 tmp[8];
#pragma unroll
            for (int e = 0; e < 8; ++e)
                tmp[e] = __float2bfloat16(smem[co_l * 160 + e * 20 + 4 * k2l + g]);
            size_t off = ((size_t)((s * NK2 + kc * 5 + k2l) * 4 + g)) * 1024
                       + (size_t)(co0 + co_l) * 8;
            *reinterpret_cast<int4*>(aT + off) = *reinterpret_cast<const int4*>(tmp);
        }
    } else {
        // ---- embed + conv1 + relu + maxpool(300)
        int blk = bid - NKT;
        int b = blk / NP1, p = blk % NP1;
        float* sig = smem;           // 304 floats
        float* red = smem + 304;     // 4 x 64
        int row0 = x[b * L + p];
        int row1 = x[b * L + p + 1];
        if (tid < 76) {
            const float* src = (tid < 75) ? (emb + (size_t)row0 * D + 4 * tid)
                                          : (emb + (size_t)row1 * D);
            *reinterpret_cast<float4*>(sig + 4 * tid) =
                *reinterpret_cast<const float4*>(src);
        }
        __syncthreads();
        int c = tid & 63, g = tid >> 6;
        float wa = w1[c * 3 + 0], wb = w1[c * 3 + 1], wc = w1[c * 3 + 2];
        float bb = b1[c];
        int jb = 76 * g;
        int ns = (g < 3) ? 19 : 18;              // g=3 covers j 228..299
        float m = -INFINITY;
        float4 cur = *reinterpret_cast<float4*>(sig + jb);   // broadcast reads
        for (int st = 0; st < ns; ++st) {
            float4 nxt = *reinterpret_cast<float4*>(sig + jb + 4 * st + 4);
            float xx[8] = {cur.x, cur.y, cur.z, cur.w, nxt.x, nxt.y, nxt.z, nxt.w};
#pragma unroll
            for (int q = 0; q < 4; ++q) {
                float v = fmaf(wc, xx[q + 2], fmaf(wb, xx[q + 1], fmaf(wa, xx[q], bb)));
                m = fmaxf(m, v);
            }
            cur = nxt;
        }
        red[g * 64 + c] = m;
        __syncthreads();
        if (tid < 64) {
            float mm = fmaxf(fmaxf(red[tid], red[64 + tid]),
                             fmaxf(red[128 + tid], red[192 + tid]));
            int sg = tid >> 3, ci = tid & 7;
            in1T[((size_t)(b * S + sg) * TPAD + p) * CI + ci] =
                __float2bfloat16(fmaxf(mm, 0.0f));
        }
    }
}

// ---------------------------------------------------------------------------
// k2_mfma: conv2 as bf16 MFMA GEMM, cin split 8 ways.
// grid 512 = 8s x 4b x 16ti (XCD-swizzled: XCD k gets s=k => 1 MB weight
// slice per XCD L2). Block: 128co x 96t, 4 waves of 64co x 48t,
// 12 mfma_16x16x32 per wave per K-step, 125 steps.
// A double-buffered + B staged via global_load_lds (linear LDS, width 16).
// ---------------------------------------------------------------------------
__global__ __launch_bounds__(256) void k2_mfma(
    const __hip_bfloat16* __restrict__ in1T,
    const __hip_bfloat16* __restrict__ aT,
    float* __restrict__ part)
{
    int wid = (blockIdx.x & 7) * 64 + (blockIdx.x >> 3);
    int s = wid >> 6, rem = wid & 63, b = rem >> 4, ti = rem & 15;
    int t0 = ti * BN;

    __shared__ __align__(16) __hip_bfloat16 seg[768 * CI];   // 12288 B
    __shared__ __align__(16) __hip_bfloat16 abuf[2][4096];   // 2 x 8192 B

    int tid = threadIdx.x;
    int w = tid >> 6, l = tid & 63;
    int lane16 = l & 15, g = l >> 4;
    int co0w = (w & 1) * 64;
    int tn0  = (w >> 1) * 48;

    // stage B: 768 rows x 16 B, contiguous in global (in1T[b][s][t][ci])
    {
        const char* gsrc = (const char*)(in1T + ((size_t)(b * S + s) * TPAD + t0) * CI);
        char* lb = (char*)seg + w * 1024;
#pragma unroll
        for (int r = 0; r < 3; ++r)
            gload_lds16(gsrc + (size_t)(r * 256 + tid) * 16, lb + r * 4096);
    }
    // stage A step 0
    const char* agbase = (const char*)(aT + (size_t)s * NK2 * 4096);
    {
        char* lb = (char*)abuf[0] + w * 1024;
        gload_lds16(agbase + (size_t)tid * 16, lb);
        gload_lds16(agbase + 4096 + (size_t)tid * 16, lb + 4096);
    }
    __syncthreads();

    f32x4 acc[4][3];
#pragma unroll
    for (int fa = 0; fa < 4; ++fa)
#pragma unroll
        for (int fb = 0; fb < 3; ++fb) acc[fa][fb] = (f32x4){0.f, 0.f, 0.f, 0.f};

    int cur = 0;
    for (int k2 = 0; k2 < NK2; ++k2) {
        if (k2 < NK2 - 1) {   // prefetch next A slice into other buffer
            const char* src = agbase + (size_t)(k2 + 1) * 8192;
            char* lb = (char*)abuf[cur ^ 1] + w * 1024;
            gload_lds16(src + (size_t)tid * 16, lb);
            gload_lds16(src + 4096 + (size_t)tid * 16, lb + 4096);
        }
        short8v af[4], bfr[3];
#pragma unroll
        for (int fa = 0; fa < 4; ++fa)
            af[fa] = *reinterpret_cast<const short8v*>(
                abuf[cur] + g * 1024 + (co0w + fa * 16 + lane16) * 8);
#pragma unroll
        for (int fb = 0; fb < 3; ++fb)
            bfr[fb] = *reinterpret_cast<const short8v*>(
                seg + (size_t)(tn0 + fb * 16 + lane16 + 4 * k2 + g) * 8);
#pragma unroll
        for (int fa = 0; fa < 4; ++fa)
#pragma unroll
            for (int fb = 0; fb < 3; ++fb)
                acc[fa][fb] = __builtin_amdgcn_mfma_f32_16x16x32_bf16(
                    af[fa], bfr[fb], acc[fa][fb], 0, 0, 0);
        __syncthreads();   // drains vmcnt: prefetched A landed; reads done
        cur ^= 1;
    }

    // epilogue: C/D layout col=lane&15 (t), row=4*g+r (co within 16)
#pragma unroll
    for (int fa = 0; fa < 4; ++fa) {
#pragma unroll
        for (int fb = 0; fb < 3; ++fb) {
            int t = t0 + tn0 + fb * 16 + lane16;
            if (t < T2) {
                int cob = co0w + fa * 16 + 4 * g;
#pragma unroll
                for (int r = 0; r < 4; ++r)
                    part[((size_t)(s * B + b) * C2 + cob + r) * T2 + t] =
                        acc[fa][fb][r];
            }
        }
    }
}

// ---------------------------------------------------------------------------
// k2b: sum 8 cin-group partials + bias, relu + maxpool(1500) -> h1[b][co]
// ---------------------------------------------------------------------------
__global__ __launch_bounds__(256) void k2b_pool(
    const float* __restrict__ part, const float* __restrict__ b2,
    float* __restrict__ h1)
{
    int bc = blockIdx.x;             // b*C2 + co
    int b = bc / C2, co = bc % C2;
    int tid = threadIdx.x;
    float m = -INFINITY;
    for (int t = tid; t < T2; t += 256) {
        float sum = 0.f;
#pragma unroll
        for (int s = 0; s < S; ++s)
            sum += part[((size_t)(s * B + b) * C2 + co) * T2 + t];
        m = fmaxf(m, sum);
    }
    __shared__ float red[256];
    red[tid] = m;
    __syncthreads();
    for (int st = 128; st > 0; st >>= 1) {
        if (tid < st) red[tid] = fmaxf(red[tid], red[tid + st]);
        __syncthreads();
    }
    if (tid == 0) h1[bc] = fmaxf(red[0] + b2[co], 0.0f);
}

// ---------------------------------------------------------------------------
// k3: lin1 + relu + lin2 + softmax. One block per batch row.
// ---------------------------------------------------------------------------
__global__ __launch_bounds__(256) void k3_head(
    const float* __restrict__ h1,
    const float* __restrict__ wl1, const float* __restrict__ bl1,
    const float* __restrict__ wl2, const float* __restrict__ bl2,
    float* __restrict__ out)
{
    int b = blockIdx.x;
    int tid = threadIdx.x;
    __shared__ float xin[C2];
    __shared__ float hbuf[HID];
    __shared__ float lg[NCLS];
    if (tid < C2) xin[tid] = h1[b * C2 + tid];
    __syncthreads();
    float a = bl1[tid];
    for (int c = 0; c < C2; ++c) a = fmaf(xin[c], wl1[tid * C2 + c], a);
    hbuf[tid] = fmaxf(a, 0.0f);
    __syncthreads();
    if (tid < NCLS) {
        float lv = bl2[tid];
        for (int j = 0; j < HID; ++j) lv = fmaf(hbuf[j], wl2[tid * HID + j], lv);
        lg[tid] = lv;
    }
    __syncthreads();
    if (tid < NCLS) {
        float mx = lg[0];
        for (int i = 1; i < NCLS; ++i) mx = fmaxf(mx, lg[i]);
        float sum = 0.f;
        for (int i = 0; i < NCLS; ++i) sum += expf(lg[i] - mx);
        out[b * NCLS + tid] = expf(lg[tid] - mx) / sum;
    }
}

extern "C" void kernel_launch(void* const* d_in, const int* in_sizes, int n_in,
                              void* d_out, int out_size, void* d_ws, size_t ws_size,
                              hipStream_t stream)
{
    const int*   x   = (const int*)  d_in[0];
    const float* emb = (const float*)d_in[1];
    const float* w1  = (const float*)d_in[2];
    const float* b1  = (const float*)d_in[3];
    const float* w2  = (const float*)d_in[4];
    const float* b2  = (const float*)d_in[5];
    const float* wl1 = (const float*)d_in[6];
    const float* bl1 = (const float*)d_in[7];
    const float* wl2 = (const float*)d_in[8];
    const float* bl2 = (const float*)d_in[9];
    float* out = (float*)d_out;

    // workspace (floats): part 8*4*128*1500 = 6,144,000 | h1 512 |
    // in1T 4*8*2304*8 bf16 = 589824 | aT 8*125*4096 bf16 = 4,096,000
    float* ws   = (float*)d_ws;
    float* part = ws;
    float* h1   = ws + (size_t)S * B * C2 * T2;
    __hip_bfloat16* in1T = (__hip_bfloat16*)(h1 + 512);
    __hip_bfloat16* aT   = in1T + (size_t)B * S * TPAD * CI;

    hipLaunchKernelGGL(k_prep, dim3(NKT + B * NP1), dim3(256), 0, stream,
                       x, emb, w1, b1, w2, in1T, aT);
    hipLaunchKernelGGL(k2_mfma, dim3(512), dim3(256), 0, stream, in1T, aT, part);
    hipLaunchKernelGGL(k2b_pool, dim3(B * C2), dim3(256), 0, stream, part, b2, h1);
    hipLaunchKernelGGL(k3_head, dim3(B), dim3(256), 0, stream,
                       h1, wl1, bl1, wl2, bl2, out);
}